// Round 11
// baseline (151.149 us; speedup 1.0000x reference)
//
#include <hip/hip_runtime.h>
#include <hip/hip_bf16.h>

#define RES 64
#define FDIM 32
// cell texture: per plane, RES*RES cells; each cell = 4 corners x 32 ch bf16
// = 256 B. Block layout: [corner0(v00)][corner1(v01)][corner2(v10)][corner3(v11)],
// each corner = 32 bf16 (ch ascending). Border clamp baked into corners.
#define CELLS_PER_PLANE (RES * RES)                  // 4096
#define CELL_ELEMS (4 * FDIM)                        // 128 bf16 per cell
#define TEX_ELEMS (3 * CELLS_PER_PLANE * CELL_ELEMS) // 1.57M bf16 = 3 MB

typedef float vfloat4 __attribute__((ext_vector_type(4)));

// ---------------------------------------------------------------------------
// Kernel 1: build the corner-duplicated bf16 cell texture from the three
// [C,H,W] f32 planes. 3 MB out, trivial cost, L2-resident afterwards.
// ---------------------------------------------------------------------------
__global__ void build_celltex(const float* __restrict__ p0,
                              const float* __restrict__ p1,
                              const float* __restrict__ p2,
                              __hip_bfloat16* __restrict__ out) {
    int e = blockIdx.x * blockDim.x + threadIdx.x;
    if (e >= TEX_ELEMS) return;
    int p      = e / (CELLS_PER_PLANE * CELL_ELEMS);
    int r      = e - p * (CELLS_PER_PLANE * CELL_ELEMS);
    int cell   = r >> 7;         // / CELL_ELEMS
    int corner = (r >> 5) & 3;
    int ch     = r & (FDIM - 1);
    int y0 = cell >> 6;
    int x0 = cell & 63;
    int y = (corner & 2) ? (y0 + 1 > RES - 1 ? RES - 1 : y0 + 1) : y0;
    int x = (corner & 1) ? (x0 + 1 > RES - 1 ? RES - 1 : x0 + 1) : x0;
    const float* in = (p == 0) ? p0 : (p == 1) ? p1 : p2;
    out[e] = __float2bfloat16(in[ch * (RES * RES) + y * RES + x]);
}

// align_corners=True bilinear coords; cell index + frac weight only
// (corner duplication already handles the x1/y1 clamp)
__device__ __forceinline__ void grid_coord(float g, int& i0, float& w) {
    g = fminf(fmaxf(g, -1.0f), 1.0f);
    float u = (g + 1.0f) * 0.5f * (float)(RES - 1);
    float f = floorf(u);
    w = u - f;
    int ii = (int)f;
    i0 = ii < 0 ? 0 : (ii > RES - 1 ? RES - 1 : ii);
}

// decode 4 bf16 (uint2, memory order ch0..ch3) to f32
__device__ __forceinline__ vfloat4 dec4(uint2 w) {
    vfloat4 f;
    f.x = __uint_as_float(w.x << 16);
    f.y = __uint_as_float(w.x & 0xffff0000u);
    f.z = __uint_as_float(w.y << 16);
    f.w = __uint_as_float(w.y & 0xffff0000u);
    return f;
}

__device__ __forceinline__ vfloat4 bilerp4(uint2 w00, uint2 w01, uint2 w10,
                                           uint2 w11, float wx, float wy) {
    vfloat4 v00 = dec4(w00), v01 = dec4(w01), v10 = dec4(w10), v11 = dec4(w11);
    float iwx = 1.0f - wx, iwy = 1.0f - wy;
    vfloat4 top = v00 * iwx + v01 * wx;
    vfloat4 bot = v10 * iwx + v11 * wx;
    return top * iwy + bot * wy;
}

// ---------------------------------------------------------------------------
// Kernel 2 (v7): cell-texture sampler + NT stores (proven) + LDS store
// reshuffle: each wave's 8 points x 384 B of results are staged in LDS and
// written as 3 x 1 KB fully-contiguous NT store instructions (lane l writes
// float4 #(64k+l) of the wave's 192-float4 span) — byte-for-byte the same
// per-instruction pattern as the 6.75 TB/s fill kernel. Single-variable A/B
// on store contiguity.
// ---------------------------------------------------------------------------
__global__ __launch_bounds__(256, 8) void kplanes_sample_celltex_sh(
    const float* __restrict__ xyz,
    const __hip_bfloat16* __restrict__ tex,  // [3][4096 cells][4][32] bf16
    float* __restrict__ out, int N) {
    __shared__ vfloat4 lds[4][192];  // 4 waves x 8 pts x 24 float4 = 12 KB

    int tid  = blockIdx.x * blockDim.x + threadIdx.x;
    int lane = threadIdx.x & 63;
    int w    = threadIdx.x >> 6;
    int pt   = tid >> 3;
    int cg   = tid & 7;        // channel group 0..7
    int p8   = lane >> 3;      // point within wave 0..7

    if (pt < N) {
        float gx = xyz[pt * 3 + 0];
        float gy = xyz[pt * 3 + 1];
        float gz = xyz[pt * 3 + 2];

        int x0, y0, z0;
        float wx, wy, wz;
        grid_coord(gx, x0, wx);
        grid_coord(gy, y0, wy);
        grid_coord(gz, z0, wz);

        // uint2 units (8 B): cell block = 32 uint2; corner k at +8k; lane +cg
        const uint2* T = (const uint2*)tex;
        const uint2* A = T + ((            (y0 << 6) + x0) << 5) + cg;
        const uint2* B = T + ((CELLS_PER_PLANE     + (z0 << 6) + x0) << 5) + cg;
        const uint2* C = T + ((2 * CELLS_PER_PLANE + (z0 << 6) + y0) << 5) + cg;

        uint2 a00 = A[0], a01 = A[8], a10 = A[16], a11 = A[24];
        uint2 b00 = B[0], b01 = B[8], b10 = B[16], b11 = B[24];
        uint2 c00 = C[0], c01 = C[8], c10 = C[16], c11 = C[24];

        int base = p8 * 24 + cg;
        lds[w][base]      = bilerp4(a00, a01, a10, a11, wx, wy);
        lds[w][base + 8]  = bilerp4(b00, b01, b10, b11, wx, wz);
        lds[w][base + 16] = bilerp4(c00, c01, c10, c11, wy, wz);
    }
    __syncthreads();

    // store phase: the wave's 8 points span 192 contiguous float4 in out
    long long f4base = ((long long)blockIdx.x * 32 + w * 8) * 24;
    long long limit  = (long long)N * 24;
    vfloat4* o = (vfloat4*)out;
#pragma unroll
    for (int k = 0; k < 3; ++k) {
        long long gi = f4base + k * 64 + lane;
        if (gi < limit) {
            vfloat4 v = lds[w][k * 64 + lane];
            __builtin_nontemporal_store(v, &o[gi]);
        }
    }
}

// ---------------------------------------------------------------------------
// Fallback (ws too small): direct f32 [C,H,W] sampling, correct but slower.
// ---------------------------------------------------------------------------
__global__ __launch_bounds__(256) void kplanes_sample_chw(
    const float* __restrict__ xyz,
    const float* __restrict__ pxy,
    const float* __restrict__ pxz,
    const float* __restrict__ pyz,
    float* __restrict__ out, int N) {
    int tid = blockIdx.x * blockDim.x + threadIdx.x;
    int pt = tid >> 3;
    int cg = tid & 7;
    if (pt >= N) return;

    float gx = xyz[pt * 3 + 0];
    float gy = xyz[pt * 3 + 1];
    float gz = xyz[pt * 3 + 2];

    int x0, y0, z0;
    float wx, wy, wz;
    grid_coord(gx, x0, wx);
    grid_coord(gy, y0, wy);
    grid_coord(gz, z0, wz);
    int x1 = x0 + 1 > RES - 1 ? RES - 1 : x0 + 1;
    int y1 = y0 + 1 > RES - 1 ? RES - 1 : y0 + 1;
    int z1 = z0 + 1 > RES - 1 ? RES - 1 : z0 + 1;

    long long obase = (long long)pt * 96 + cg * 4;

    const float* planes[3] = {pxy, pxz, pyz};
    int a0[3] = {y0 * RES + x0, z0 * RES + x0, z0 * RES + y0};
    int a1[3] = {y0 * RES + x1, z0 * RES + x1, z0 * RES + y1};
    int a2[3] = {y1 * RES + x0, z1 * RES + x0, z1 * RES + y0};
    int a3[3] = {y1 * RES + x1, z1 * RES + x1, z1 * RES + y1};
    float wwx[3] = {wx, wx, wy};
    float wwy[3] = {wy, wz, wz};

#pragma unroll
    for (int p = 0; p < 3; ++p) {
        const float* Bp = planes[p];
#pragma unroll
        for (int k = 0; k < 4; ++k) {
            int c = cg * 4 + k;
            const float* Bc = Bp + c * (RES * RES);
            float v00 = Bc[a0[p]];
            float v01 = Bc[a1[p]];
            float v10 = Bc[a2[p]];
            float v11 = Bc[a3[p]];
            float top = v00 * (1.0f - wwx[p]) + v01 * wwx[p];
            float bot = v10 * (1.0f - wwx[p]) + v11 * wwx[p];
            out[obase + p * 32 + k] = top * (1.0f - wwy[p]) + bot * wwy[p];
        }
    }
}

extern "C" void kernel_launch(void* const* d_in, const int* in_sizes, int n_in,
                              void* d_out, int out_size, void* d_ws, size_t ws_size,
                              hipStream_t stream) {
    const float* xyz = (const float*)d_in[0];
    const float* pxy = (const float*)d_in[1];
    const float* pxz = (const float*)d_in[2];
    const float* pyz = (const float*)d_in[3];
    float* out = (float*)d_out;
    int N = in_sizes[0] / 3;

    size_t need = (size_t)TEX_ELEMS * sizeof(__hip_bfloat16);  // 3 MB
    long long total = (long long)N * 8;
    int grid = (int)((total + 255) / 256);

    if (ws_size >= need) {
        __hip_bfloat16* ws = (__hip_bfloat16*)d_ws;
        build_celltex<<<(TEX_ELEMS + 255) / 256, 256, 0, stream>>>(
            pxy, pxz, pyz, ws);
        kplanes_sample_celltex_sh<<<grid, 256, 0, stream>>>(xyz, ws, out, N);
    } else {
        kplanes_sample_chw<<<grid, 256, 0, stream>>>(xyz, pxy, pxz, pyz, out, N);
    }
}

// Round 12
// 146.033 us; speedup vs baseline: 1.0350x; 1.0350x over previous
//
#include <hip/hip_runtime.h>
#include <hip/hip_bf16.h>

#define RES 64
#define FDIM 32
// cell texture: per plane, RES*RES cells; each cell = 4 corners x 32 ch bf16
// = 256 B. Block layout: [corner0(v00)][corner1(v01)][corner2(v10)][corner3(v11)],
// each corner = 32 bf16 (ch ascending). Border clamp baked into corners.
#define CELLS_PER_PLANE (RES * RES)                  // 4096
#define CELL_ELEMS (4 * FDIM)                        // 128 bf16 per cell
#define TEX_ELEMS (3 * CELLS_PER_PLANE * CELL_ELEMS) // 1.57M bf16 = 3 MB

typedef float vfloat4 __attribute__((ext_vector_type(4)));

// ---------------------------------------------------------------------------
// Kernel 1: build the corner-duplicated bf16 cell texture from the three
// [C,H,W] f32 planes. 3 MB out, trivial cost, L2-resident afterwards.
// ---------------------------------------------------------------------------
__global__ void build_celltex(const float* __restrict__ p0,
                              const float* __restrict__ p1,
                              const float* __restrict__ p2,
                              __hip_bfloat16* __restrict__ out) {
    int e = blockIdx.x * blockDim.x + threadIdx.x;
    if (e >= TEX_ELEMS) return;
    int p      = e / (CELLS_PER_PLANE * CELL_ELEMS);
    int r      = e - p * (CELLS_PER_PLANE * CELL_ELEMS);
    int cell   = r >> 7;         // / CELL_ELEMS
    int corner = (r >> 5) & 3;
    int ch     = r & (FDIM - 1);
    int y0 = cell >> 6;
    int x0 = cell & 63;
    int y = (corner & 2) ? (y0 + 1 > RES - 1 ? RES - 1 : y0 + 1) : y0;
    int x = (corner & 1) ? (x0 + 1 > RES - 1 ? RES - 1 : x0 + 1) : x0;
    const float* in = (p == 0) ? p0 : (p == 1) ? p1 : p2;
    out[e] = __float2bfloat16(in[ch * (RES * RES) + y * RES + x]);
}

// align_corners=True bilinear coords; cell index + frac weight only
// (corner duplication already handles the x1/y1 clamp)
__device__ __forceinline__ void grid_coord(float g, int& i0, float& w) {
    g = fminf(fmaxf(g, -1.0f), 1.0f);
    float u = (g + 1.0f) * 0.5f * (float)(RES - 1);
    float f = floorf(u);
    w = u - f;
    int ii = (int)f;
    i0 = ii < 0 ? 0 : (ii > RES - 1 ? RES - 1 : ii);
}

// decode 4 bf16 (packed in uint2, memory order ch0..ch3) to f32
__device__ __forceinline__ vfloat4 dec4(uint2 w) {
    vfloat4 f;
    f.x = __uint_as_float(w.x << 16);
    f.y = __uint_as_float(w.x & 0xffff0000u);
    f.z = __uint_as_float(w.y << 16);
    f.w = __uint_as_float(w.y & 0xffff0000u);
    return f;
}

__device__ __forceinline__ vfloat4 bilerp4(uint2 w00, uint2 w01, uint2 w10,
                                           uint2 w11, float wx, float wy) {
    vfloat4 v00 = dec4(w00), v01 = dec4(w01), v10 = dec4(w10), v11 = dec4(w11);
    float iwx = 1.0f - wx, iwy = 1.0f - wy;
    vfloat4 top = v00 * iwx + v01 * wx;
    vfloat4 bot = v10 * iwx + v11 * wx;
    return top * iwy + bot * wy;
}

// ---------------------------------------------------------------------------
// Kernel 2 (final, proven best = round-9): cell-texture sampler with
// NONTEMPORAL stores (the +109 us lever — round-8 A/B) and max-occupancy
// launch bounds. 8 threads/point; thread cg handles channels [4cg,4cg+4).
// Per plane the point reads ONE contiguous 256 B cell block (4 x uint2,
// 2 cache lines). Stores: one float4 per plane, NT so the 768 MB write
// stream doesn't thrash L2 (which must hold the 3 MB texture).
// ---------------------------------------------------------------------------
__global__ __launch_bounds__(256, 8) void kplanes_sample_celltex(
    const float* __restrict__ xyz,
    const __hip_bfloat16* __restrict__ tex,  // [3][4096 cells][4][32] bf16
    float* __restrict__ out, int N) {
    int tid = blockIdx.x * blockDim.x + threadIdx.x;
    int pt = tid >> 3;
    int cg = tid & 7;
    if (pt >= N) return;

    float gx = xyz[pt * 3 + 0];
    float gy = xyz[pt * 3 + 1];
    float gz = xyz[pt * 3 + 2];

    int x0, y0, z0;
    float wx, wy, wz;
    grid_coord(gx, x0, wx);
    grid_coord(gy, y0, wy);
    grid_coord(gz, z0, wz);

    // uint2 units (8 B): cell block = 32 uint2; corner k at +8k; lane at +cg
    const uint2* T = (const uint2*)tex;
    const uint2* A = T + ((            (y0 << 6) + x0) << 5) + cg;  // plane_xy
    const uint2* B = T + ((CELLS_PER_PLANE     + (z0 << 6) + x0) << 5) + cg;  // plane_xz
    const uint2* C = T + ((2 * CELLS_PER_PLANE + (z0 << 6) + y0) << 5) + cg;  // plane_yz

    uint2 a00 = A[0], a01 = A[8], a10 = A[16], a11 = A[24];
    uint2 b00 = B[0], b01 = B[8], b10 = B[16], b11 = B[24];
    uint2 c00 = C[0], c01 = C[8], c10 = C[16], c11 = C[24];

    vfloat4* o = (vfloat4*)out;  // row stride = 24 float4
    long long orow = (long long)pt * 24 + cg;

    vfloat4 r0 = bilerp4(a00, a01, a10, a11, wx, wy);
    __builtin_nontemporal_store(r0, &o[orow]);
    vfloat4 r1 = bilerp4(b00, b01, b10, b11, wx, wz);
    __builtin_nontemporal_store(r1, &o[orow + 8]);
    vfloat4 r2 = bilerp4(c00, c01, c10, c11, wy, wz);
    __builtin_nontemporal_store(r2, &o[orow + 16]);
}

// ---------------------------------------------------------------------------
// Fallback (ws too small): direct f32 [C,H,W] sampling, correct but slower.
// ---------------------------------------------------------------------------
__global__ __launch_bounds__(256) void kplanes_sample_chw(
    const float* __restrict__ xyz,
    const float* __restrict__ pxy,
    const float* __restrict__ pxz,
    const float* __restrict__ pyz,
    float* __restrict__ out, int N) {
    int tid = blockIdx.x * blockDim.x + threadIdx.x;
    int pt = tid >> 3;
    int cg = tid & 7;
    if (pt >= N) return;

    float gx = xyz[pt * 3 + 0];
    float gy = xyz[pt * 3 + 1];
    float gz = xyz[pt * 3 + 2];

    int x0, y0, z0;
    float wx, wy, wz;
    grid_coord(gx, x0, wx);
    grid_coord(gy, y0, wy);
    grid_coord(gz, z0, wz);
    int x1 = x0 + 1 > RES - 1 ? RES - 1 : x0 + 1;
    int y1 = y0 + 1 > RES - 1 ? RES - 1 : y0 + 1;
    int z1 = z0 + 1 > RES - 1 ? RES - 1 : z0 + 1;

    long long obase = (long long)pt * 96 + cg * 4;

    const float* planes[3] = {pxy, pxz, pyz};
    int a0[3] = {y0 * RES + x0, z0 * RES + x0, z0 * RES + y0};
    int a1[3] = {y0 * RES + x1, z0 * RES + x1, z0 * RES + y1};
    int a2[3] = {y1 * RES + x0, z1 * RES + x0, z1 * RES + y0};
    int a3[3] = {y1 * RES + x1, z1 * RES + x1, z1 * RES + y1};
    float wwx[3] = {wx, wx, wy};
    float wwy[3] = {wy, wz, wz};

#pragma unroll
    for (int p = 0; p < 3; ++p) {
        const float* Bp = planes[p];
#pragma unroll
        for (int k = 0; k < 4; ++k) {
            int c = cg * 4 + k;
            const float* Bc = Bp + c * (RES * RES);
            float v00 = Bc[a0[p]];
            float v01 = Bc[a1[p]];
            float v10 = Bc[a2[p]];
            float v11 = Bc[a3[p]];
            float top = v00 * (1.0f - wwx[p]) + v01 * wwx[p];
            float bot = v10 * (1.0f - wwx[p]) + v11 * wwx[p];
            out[obase + p * 32 + k] = top * (1.0f - wwy[p]) + bot * wwy[p];
        }
    }
}

extern "C" void kernel_launch(void* const* d_in, const int* in_sizes, int n_in,
                              void* d_out, int out_size, void* d_ws, size_t ws_size,
                              hipStream_t stream) {
    const float* xyz = (const float*)d_in[0];
    const float* pxy = (const float*)d_in[1];
    const float* pxz = (const float*)d_in[2];
    const float* pyz = (const float*)d_in[3];
    float* out = (float*)d_out;
    int N = in_sizes[0] / 3;

    size_t need = (size_t)TEX_ELEMS * sizeof(__hip_bfloat16);  // 3 MB
    long long total = (long long)N * 8;
    int grid = (int)((total + 255) / 256);

    if (ws_size >= need) {
        __hip_bfloat16* ws = (__hip_bfloat16*)d_ws;
        build_celltex<<<(TEX_ELEMS + 255) / 256, 256, 0, stream>>>(
            pxy, pxz, pyz, ws);
        kplanes_sample_celltex<<<grid, 256, 0, stream>>>(xyz, ws, out, N);
    } else {
        kplanes_sample_chw<<<grid, 256, 0, stream>>>(xyz, pxy, pxz, pyz, out, N);
    }
}